// Round 1
// baseline (1281.921 us; speedup 1.0000x reference)
//
#include <hip/hip_runtime.h>

typedef _Float16 half_t;
typedef __attribute__((ext_vector_type(4))) _Float16 half4;
typedef __attribute__((ext_vector_type(8))) _Float16 half8;
typedef __attribute__((ext_vector_type(4))) float f32x4;

#define BATCH  16384
#define BASE   1008
#define BASEP  1024
#define NB     5
#define ROWS_P 17024      // 16384 + 5*128 (segment alignment slack)
#define MT_DENSE 133      // ROWS_P / 128

__constant__ int d_sizes[NB] = {36, 72, 144, 288, 1008};
__constant__ int d_ka[NB]    = {64, 96, 160, 288, 1024};   // align32(s)

__device__ __forceinline__ int bucket_of(int s) {
    return (s == 36) ? 0 : (s == 72) ? 1 : (s == 144) ? 2 : (s == 288) ? 3 : 4;
}

// ---------------- ws layout (bytes) ----------------
constexpr size_t OFF_META = 0;                                   // 16 ints: cnt[5], seg[5], cur[5]
constexpr size_t OFF_PERM = 256;                                 // ROWS_P ints = 68096 B
constexpr size_t OFF_XH   = 68352;                               // fp16 [ROWS_P][1024]
constexpr size_t SZ1024   = (size_t)ROWS_P * 1024 * 2;
constexpr size_t OFF_E    = OFF_XH + SZ1024;                     // fp16 [ROWS_P][1024]
constexpr size_t OFF_B512 = OFF_E + SZ1024;                      // fp16 [ROWS_P][512]
constexpr size_t OFF_C256 = OFF_B512 + (size_t)ROWS_P * 512 * 2; // fp16 [ROWS_P][256]
constexpr size_t OFF_D128 = OFF_C256 + (size_t)ROWS_P * 256 * 2; // fp16 [ROWS_P][128]
constexpr size_t OFF_WIN  = OFF_D128 + (size_t)ROWS_P * 128 * 2; // fp16 [5][1024][1024]
constexpr size_t OFF_WOUT = OFF_WIN  + (size_t)NB * 1024 * 1024 * 2;
constexpr size_t OFF_WE1  = OFF_WOUT + (size_t)NB * 1024 * 1024 * 2; // [512][1024]
constexpr size_t OFF_WE2  = OFF_WE1 + (size_t)512 * 1024 * 2;        // [256][512]
constexpr size_t OFF_WE3  = OFF_WE2 + (size_t)256 * 512 * 2;         // [128][256]
constexpr size_t OFF_WD1  = OFF_WE3 + (size_t)128 * 256 * 2;         // [256][128]
constexpr size_t OFF_WD2  = OFF_WD1 + (size_t)256 * 128 * 2;         // [512][256]
constexpr size_t OFF_WD3  = OFF_WD2 + (size_t)512 * 256 * 2;         // [1024][512]
constexpr size_t WS_NEED  = OFF_WD3 + (size_t)1024 * 512 * 2;        // ~118 MB

// ---------------- prep kernels ----------------
__global__ void hist_kernel(const int* __restrict__ seq, int* __restrict__ meta) {
    __shared__ int lc[NB];
    if (threadIdx.x < NB) lc[threadIdx.x] = 0;
    __syncthreads();
    int b = blockIdx.x * blockDim.x + threadIdx.x;
    if (b < BATCH) atomicAdd(&lc[bucket_of(seq[b])], 1);
    __syncthreads();
    if (threadIdx.x < NB) atomicAdd(&meta[threadIdx.x], lc[threadIdx.x]);
}

__global__ void prefix_kernel(int* __restrict__ meta) {
    if (threadIdx.x == 0 && blockIdx.x == 0) {
        int off = 0;
        for (int k = 0; k < NB; k++) {
            meta[5 + k] = off;                       // seg_start (128-aligned)
            off += (meta[k] + 127) & ~127;
            meta[10 + k] = 0;                        // cursor
        }
    }
}

// one row per block iteration: emit permutation + convert/pad x to fp16
__global__ void scatter_kernel(const float* __restrict__ x, const int* __restrict__ seq,
                               int* __restrict__ meta, int* __restrict__ perm,
                               half_t* __restrict__ xh) {
    __shared__ int pos_s;
    for (int b = blockIdx.x; b < BATCH; b += gridDim.x) {
        if (threadIdx.x == 0) {
            int k = bucket_of(seq[b]);
            int p = meta[5 + k] + atomicAdd(&meta[10 + k], 1);
            perm[p] = b;
            pos_s = p;
        }
        __syncthreads();
        int pos = pos_s;
        int c = threadIdx.x * 4;  // 0..1020
        half4 o4;
        if (c < BASE) {
            float4 v = *reinterpret_cast<const float4*>(x + (size_t)b * BASE + c);
            o4.x = (half_t)v.x; o4.y = (half_t)v.y; o4.z = (half_t)v.z; o4.w = (half_t)v.w;
        } else {
            o4.x = o4.y = o4.z = o4.w = (half_t)0.0f;
        }
        *reinterpret_cast<half4*>(xh + (size_t)pos * BASEP + c) = o4;
        __syncthreads();
    }
}

// generic fp32 -> fp16 convert with zero padding; Cp = 1<<cshift, blockIdx.z batches matrices
__global__ void conv_pad(const float* __restrict__ src, half_t* __restrict__ dst,
                         int R, int C, int Rp, int cshift) {
    int Cp = 1 << cshift;
    size_t base_s = (size_t)blockIdx.z * R * C;
    size_t base_d = ((size_t)blockIdx.z * Rp) << cshift;
    int total = Rp << cshift;
    for (int i = blockIdx.x * blockDim.x + threadIdx.x; i < total; i += gridDim.x * blockDim.x) {
        int r = i >> cshift, c = i & (Cp - 1);
        float v = (r < R && c < C) ? src[base_s + (size_t)r * C + c] : 0.0f;
        dst[base_d + i] = (half_t)v;
    }
}

// ---------------- GEMM ----------------
// MODE 0: dense   Y[M,Npad] = act(A[M,K] @ W[Npad,K]^T + bias)
// MODE 1: expand  (per-bucket z): A = xh rows of segment, K = d_ka[z], W = Win_h[z]
// MODE 2: contract(per-bucket z): fp32 scatter-store to d_out via perm, N tiles cut at s_z
template <int MODE, bool RELU>
__global__ __launch_bounds__(256)
void gemm_k(const half_t* __restrict__ Abase, const half_t* __restrict__ Wbase,
            const float* __restrict__ biasbase, half_t* __restrict__ Obase,
            float* __restrict__ out32, const int* __restrict__ meta,
            const int* __restrict__ perm, int Kdense, int Npad, int Nreal) {
    const int tid  = threadIdx.x;
    const int lane = tid & 63;
    const int wave = tid >> 6;
    const int mtile = blockIdx.x, ntile = blockIdx.y;

    int K, ld, rowbase, cnt = 0;
    const half_t* A;
    const half_t* W;
    const float* bias;
    if (MODE == 0) {
        K = Kdense; ld = Kdense;
        rowbase = mtile * 128;
        A = Abase + (size_t)rowbase * ld;
        W = Wbase + (size_t)ntile * 128 * ld;
        bias = biasbase;
    } else {
        int kb = blockIdx.z;
        cnt = meta[kb];
        int cnt_pad = (cnt + 127) & ~127;
        if (mtile * 128 >= cnt_pad) return;
        if (MODE == 2 && ntile * 128 >= d_sizes[kb]) return;
        ld = BASEP;
        K = (MODE == 1) ? d_ka[kb] : BASEP;
        rowbase = meta[5 + kb] + mtile * 128;
        A = Abase + (size_t)rowbase * BASEP;
        W = Wbase + (size_t)kb * BASEP * BASEP + (size_t)ntile * 128 * BASEP;
        bias = biasbase + kb * BASE;
    }

    __shared__ __align__(16) half_t As[128 * 32];
    __shared__ __align__(16) half_t Bs[128 * 32];

    f32x4 acc[4][4];
#pragma unroll
    for (int m = 0; m < 4; m++)
#pragma unroll
        for (int n = 0; n < 4; n++)
            acc[m][n] = (f32x4){0.f, 0.f, 0.f, 0.f};

    const int wr = (wave >> 1) * 64;   // wave's row quadrant
    const int wc = (wave & 1) * 64;    // wave's col quadrant
    const int fr = lane & 15;
    const int kc = lane >> 4;          // k-chunk 0..3
    const int wbase = tid & ~63;       // linear idx of lane0 of this wave

    for (int k0 = 0; k0 < K; k0 += 32) {
#pragma unroll
        for (int i = 0; i < 2; i++) {
            int idx = i * 256 + tid;
            int row = idx >> 2, ch = idx & 3;
            const half_t* ga = A + (size_t)row * ld + (k0 + ch * 8);
            const half_t* gb = W + (size_t)row * ld + (k0 + ch * 8);
            half_t* la = As + (size_t)(i * 256 + wbase) * 8;
            half_t* lb = Bs + (size_t)(i * 256 + wbase) * 8;
            __builtin_amdgcn_global_load_lds((__attribute__((address_space(1))) void*)(ga),
                                             (__attribute__((address_space(3))) void*)(la), 16, 0, 0);
            __builtin_amdgcn_global_load_lds((__attribute__((address_space(1))) void*)(gb),
                                             (__attribute__((address_space(3))) void*)(lb), 16, 0, 0);
        }
        __syncthreads();   // drains vmcnt before barrier (compiler-inserted)

        half8 af[4], bf[4];
#pragma unroll
        for (int m = 0; m < 4; m++)
            af[m] = *reinterpret_cast<const half8*>(&As[(wr + m * 16 + fr) * 32 + kc * 8]);
#pragma unroll
        for (int n = 0; n < 4; n++)
            bf[n] = *reinterpret_cast<const half8*>(&Bs[(wc + n * 16 + fr) * 32 + kc * 8]);
#pragma unroll
        for (int m = 0; m < 4; m++)
#pragma unroll
            for (int n = 0; n < 4; n++)
                acc[m][n] = __builtin_amdgcn_mfma_f32_16x16x32_f16(af[m], bf[n], acc[m][n], 0, 0, 0);
        __syncthreads();   // protect LDS from next iteration's staging
    }

    // epilogue: D row = (lane>>4)*4 + j, col = lane&15  (m89-verified layout)
    float bv[4];
#pragma unroll
    for (int n = 0; n < 4; n++) {
        int col = ntile * 128 + wc + n * 16 + fr;
        bv[n] = (col < Nreal) ? bias[col] : 0.0f;
    }
#pragma unroll
    for (int m = 0; m < 4; m++) {
#pragma unroll
        for (int j = 0; j < 4; j++) {
            int r = wr + m * 16 + kc * 4 + j;
#pragma unroll
            for (int n = 0; n < 4; n++) {
                float v = acc[m][n][j] + bv[n];
                if (RELU) v = fmaxf(v, 0.0f);
                int c = wc + n * 16 + fr;
                if (MODE == 2) {
                    if (mtile * 128 + r < cnt) {
                        int col = ntile * 128 + c;
                        if (col < BASE) {
                            int orig = perm[rowbase + r];
                            out32[(size_t)orig * BASE + col] = v;
                        }
                    }
                } else {
                    Obase[(size_t)(rowbase + r) * Npad + ntile * 128 + c] = (half_t)v;
                }
            }
        }
    }
}

// ---------------- launch ----------------
extern "C" void kernel_launch(void* const* d_in, const int* in_sizes, int n_in,
                              void* d_out, int out_size, void* d_ws, size_t ws_size,
                              hipStream_t stream) {
    (void)in_sizes; (void)n_in;
    if (ws_size < WS_NEED) return;  // workspace too small: fail loudly via wrong output

    const float* x    = (const float*)d_in[0];
    const int*   seq  = (const int*)d_in[1];
    const float* Win  = (const float*)d_in[2];
    const float* bin_ = (const float*)d_in[3];
    const float* Wout = (const float*)d_in[4];
    const float* bout = (const float*)d_in[5];
    const float* We1  = (const float*)d_in[6];  const float* be1 = (const float*)d_in[7];
    const float* We2  = (const float*)d_in[8];  const float* be2 = (const float*)d_in[9];
    const float* We3  = (const float*)d_in[10]; const float* be3 = (const float*)d_in[11];
    const float* Wd1  = (const float*)d_in[12]; const float* bd1 = (const float*)d_in[13];
    const float* Wd2  = (const float*)d_in[14]; const float* bd2 = (const float*)d_in[15];
    const float* Wd3  = (const float*)d_in[16]; const float* bd3 = (const float*)d_in[17];

    char* ws = (char*)d_ws;
    int*    meta = (int*)(ws + OFF_META);
    int*    perm = (int*)(ws + OFF_PERM);
    half_t* xh   = (half_t*)(ws + OFF_XH);
    half_t* E    = (half_t*)(ws + OFF_E);
    half_t* B512 = (half_t*)(ws + OFF_B512);
    half_t* C256 = (half_t*)(ws + OFF_C256);
    half_t* D128 = (half_t*)(ws + OFF_D128);
    half_t* winh = (half_t*)(ws + OFF_WIN);
    half_t* wouth= (half_t*)(ws + OFF_WOUT);
    half_t* we1h = (half_t*)(ws + OFF_WE1);
    half_t* we2h = (half_t*)(ws + OFF_WE2);
    half_t* we3h = (half_t*)(ws + OFF_WE3);
    half_t* wd1h = (half_t*)(ws + OFF_WD1);
    half_t* wd2h = (half_t*)(ws + OFF_WD2);
    half_t* wd3h = (half_t*)(ws + OFF_WD3);
    float*  out  = (float*)d_out;

    hipMemsetAsync(meta, 0, 64, stream);
    hipMemsetAsync(d_out, 0, (size_t)out_size * sizeof(float), stream);

    hist_kernel<<<64, 256, 0, stream>>>(seq, meta);
    prefix_kernel<<<1, 64, 0, stream>>>(meta);
    scatter_kernel<<<2048, 256, 0, stream>>>(x, seq, meta, perm, xh);

    conv_pad<<<dim3(512, 1, NB), 256, 0, stream>>>(Win,  winh, 1008, 1008, 1024, 10);
    conv_pad<<<dim3(512, 1, NB), 256, 0, stream>>>(Wout, wouth, 1008, 1008, 1024, 10);
    conv_pad<<<dim3(512, 1, 1), 256, 0, stream>>>(We1, we1h,  512, 1008,  512, 10);
    conv_pad<<<dim3(128, 1, 1), 256, 0, stream>>>(We2, we2h,  256,  512,  256,  9);
    conv_pad<<<dim3(64, 1, 1),  256, 0, stream>>>(We3, we3h,  128,  256,  128,  8);
    conv_pad<<<dim3(64, 1, 1),  256, 0, stream>>>(Wd1, wd1h,  256,  128,  256,  7);
    conv_pad<<<dim3(128, 1, 1), 256, 0, stream>>>(Wd2, wd2h,  512,  256,  512,  8);
    conv_pad<<<dim3(512, 1, 1), 256, 0, stream>>>(Wd3, wd3h, 1008,  512, 1024,  9);

    // expand: per-bucket K-trimmed GEMM, xh -> E [.,1024]
    gemm_k<1, false><<<dim3(128, 8, NB), 256, 0, stream>>>(xh, winh, bin_, E, nullptr, meta, perm, 0, 1024, 1008);
    // encoder
    gemm_k<0, true ><<<dim3(MT_DENSE, 4), 256, 0, stream>>>(E,    we1h, be1, B512, nullptr, meta, perm, 1024, 512, 512);
    gemm_k<0, true ><<<dim3(MT_DENSE, 2), 256, 0, stream>>>(B512, we2h, be2, C256, nullptr, meta, perm,  512, 256, 256);
    gemm_k<0, false><<<dim3(MT_DENSE, 1), 256, 0, stream>>>(C256, we3h, be3, D128, nullptr, meta, perm,  256, 128, 128);
    // decoder
    gemm_k<0, true ><<<dim3(MT_DENSE, 2), 256, 0, stream>>>(D128, wd1h, bd1, C256, nullptr, meta, perm,  128, 256, 256);
    gemm_k<0, true ><<<dim3(MT_DENSE, 4), 256, 0, stream>>>(C256, wd2h, bd2, B512, nullptr, meta, perm,  256, 512, 512);
    gemm_k<0, false><<<dim3(MT_DENSE, 8), 256, 0, stream>>>(B512, wd3h, bd3, E,    nullptr, meta, perm,  512, 1024, 1008);
    // contract: per-bucket N-tile-cut GEMM, scatter fp32 rows into pre-zeroed d_out
    gemm_k<2, false><<<dim3(128, 8, NB), 256, 0, stream>>>(E, wouth, bout, nullptr, out, meta, perm, 1024, 1024, 1008);
}

// Round 3
// 445.577 us; speedup vs baseline: 2.8770x; 2.8770x over previous
//
#include <hip/hip_runtime.h>

typedef _Float16 half_t;
typedef __attribute__((ext_vector_type(4))) _Float16 half4;
typedef __attribute__((ext_vector_type(8))) _Float16 half8;
typedef __attribute__((ext_vector_type(4))) float f32x4;

#define BATCH  16384
#define BASE   1008
#define BASEP  1024
#define NB     5
#define ROWS_P 17024      // 16384 + 5*128 (segment alignment slack)
#define MT_DENSE 133      // ROWS_P / 128
#define NBLK   64         // BATCH / 256

__constant__ int d_sizes[NB] = {36, 72, 144, 288, 1008};
__constant__ int d_ka[NB]    = {64, 96, 160, 288, 1024};   // align32(s)

__device__ __forceinline__ int bucket_of(int s) {
    return (s == 36) ? 0 : (s == 72) ? 1 : (s == 144) ? 2 : (s == 288) ? 3 : 4;
}

// ---------------- ws layout (bytes) ----------------
// meta: [0..4]=cnt, [5..9]=seg_start (128-aligned)
constexpr size_t OFF_META = 0;                                   // 256 B reserved
constexpr size_t OFF_PERM = 256;                                 // ROWS_P ints
constexpr size_t OFF_RANK = OFF_PERM + (size_t)ROWS_P * 4;       // BATCH ints
constexpr size_t OFF_POS  = OFF_RANK + (size_t)BATCH * 4;        // BATCH ints
constexpr size_t OFF_BLKT = OFF_POS  + (size_t)BATCH * 4;        // NBLK*NB ints
constexpr size_t OFF_BLKB = OFF_BLKT + (size_t)NBLK * NB * 4;    // NBLK*NB ints
constexpr size_t OFF_XH   = (OFF_BLKB + (size_t)NBLK * NB * 4 + 255) & ~(size_t)255;
constexpr size_t SZ1024   = (size_t)ROWS_P * 1024 * 2;
constexpr size_t OFF_E    = OFF_XH + SZ1024;                     // fp16 [ROWS_P][1024]
constexpr size_t OFF_B512 = OFF_E + SZ1024;                      // fp16 [ROWS_P][512]
constexpr size_t OFF_C256 = OFF_B512 + (size_t)ROWS_P * 512 * 2; // fp16 [ROWS_P][256]
constexpr size_t OFF_D128 = OFF_C256 + (size_t)ROWS_P * 256 * 2; // fp16 [ROWS_P][128]
constexpr size_t OFF_WIN  = OFF_D128 + (size_t)ROWS_P * 128 * 2; // fp16 [5][1024][1024]
constexpr size_t OFF_WOUT = OFF_WIN  + (size_t)NB * 1024 * 1024 * 2;
constexpr size_t OFF_WE1  = OFF_WOUT + (size_t)NB * 1024 * 1024 * 2; // [512][1024]
constexpr size_t OFF_WE2  = OFF_WE1 + (size_t)512 * 1024 * 2;        // [256][512]
constexpr size_t OFF_WE3  = OFF_WE2 + (size_t)256 * 512 * 2;         // [128][256]
constexpr size_t OFF_WD1  = OFF_WE3 + (size_t)128 * 256 * 2;         // [256][128]
constexpr size_t OFF_WD2  = OFF_WD1 + (size_t)256 * 128 * 2;         // [512][256]
constexpr size_t OFF_WD3  = OFF_WD2 + (size_t)512 * 256 * 2;         // [1024][512]
constexpr size_t WS_NEED  = OFF_WD3 + (size_t)1024 * 512 * 2;        // ~118.4 MiB

// ---------------- deterministic permutation (no atomics anywhere) ----------------
// Stage 1: per-block, per-wave ballot ranks. rankb[b] = rank of b within its
// block+bucket (deterministic: lane order); blk_tot[blk][k] = block histogram.
__global__ void rank_kernel(const int* __restrict__ seq, int* __restrict__ rankb,
                            int* __restrict__ blk_tot) {
    __shared__ int wcnt[4][NB];
    __shared__ int wbase[4][NB];
    const int tid = threadIdx.x, lane = tid & 63, wave = tid >> 6;
    const int b = blockIdx.x * 256 + tid;
    const int k = bucket_of(seq[b]);
    unsigned long long same = 0;
#pragma unroll
    for (int kk = 0; kk < NB; kk++) {
        unsigned long long mk = __ballot(k == kk);
        if (lane == 0) wcnt[wave][kk] = __popcll(mk);
        if (k == kk) same = mk;
    }
    const int lr = __popcll(same & ((1ull << lane) - 1ull));
    __syncthreads();
    if (tid < NB) {                       // tid = bucket index
        int s = 0;
#pragma unroll
        for (int w = 0; w < 4; w++) { wbase[w][tid] = s; s += wcnt[w][tid]; }
        blk_tot[blockIdx.x * NB + tid] = s;
    }
    __syncthreads();
    rankb[b] = wbase[wave][k] + lr;
}

// Stage 2: single block — bucket totals, segment starts, per-block bases.
__global__ void base_kernel(const int* __restrict__ blk_tot, int* __restrict__ meta,
                            int* __restrict__ blkbase) {
    __shared__ int tot[NB], seg[NB];
    const int tid = threadIdx.x;
    if (tid < NB) {
        int s = 0;
        for (int blk = 0; blk < NBLK; blk++) {
            blkbase[blk * NB + tid] = s;
            s += blk_tot[blk * NB + tid];
        }
        tot[tid] = s;
    }
    __syncthreads();
    if (tid == 0) {
        int off = 0;
        for (int kk = 0; kk < NB; kk++) {
            seg[kk] = off;
            meta[kk] = tot[kk];
            meta[5 + kk] = off;
            off += (tot[kk] + 127) & ~127;
        }
    }
    __syncthreads();
    if (tid < NB)
        for (int blk = 0; blk < NBLK; blk++) blkbase[blk * NB + tid] += seg[tid];
}

// Stage 3: elementwise finalize — fully deterministic perm/pos.
__global__ void finalize_kernel(const int* __restrict__ seq, const int* __restrict__ rankb,
                                const int* __restrict__ blkbase, int* __restrict__ perm,
                                int* __restrict__ pos) {
    const int b = blockIdx.x * 256 + threadIdx.x;
    const int k = bucket_of(seq[b]);
    const int p = blkbase[blockIdx.x * NB + k] + rankb[b];
    perm[p] = b;
    pos[b] = p;
}

// Zero xh segment-padding rows [seg+cnt, seg+align128(cnt)) so no GEMM input is
// ever read-before-write (launch-invariant state => bit-identical launches).
__global__ void zero_xh_pad(const int* __restrict__ meta, half_t* __restrict__ xh) {
    const int kb = blockIdx.y;
    const int cnt = meta[kb];
    const int cnt_pad = (cnt + 127) & ~127;
    const int r = cnt + blockIdx.x;
    if (r >= cnt_pad) return;
    const int row = meta[5 + kb] + r;
    half4 z; z.x = z.y = z.z = z.w = (half_t)0.0f;
    *reinterpret_cast<half4*>(xh + (size_t)row * BASEP + threadIdx.x * 4) = z;
}

// Pure coalesced convert+scatter: no atomics, no syncthreads.
__global__ void copy_convert_kernel(const float* __restrict__ x, const int* __restrict__ pos,
                                    half_t* __restrict__ xh) {
    for (int b = blockIdx.x; b < BATCH; b += gridDim.x) {
        int p = pos[b];
        int c = threadIdx.x * 4;  // 0..1020
        half4 o4;
        if (c < BASE) {
            float4 v = *reinterpret_cast<const float4*>(x + (size_t)b * BASE + c);
            o4.x = (half_t)v.x; o4.y = (half_t)v.y; o4.z = (half_t)v.z; o4.w = (half_t)v.w;
        } else {
            o4.x = o4.y = o4.z = o4.w = (half_t)0.0f;
        }
        *reinterpret_cast<half4*>(xh + (size_t)p * BASEP + c) = o4;
    }
}

// generic fp32 -> fp16 convert with zero padding; Cp = 1<<cshift, blockIdx.z batches matrices
__global__ void conv_pad(const float* __restrict__ src, half_t* __restrict__ dst,
                         int R, int C, int Rp, int cshift) {
    int Cp = 1 << cshift;
    size_t base_s = (size_t)blockIdx.z * R * C;
    size_t base_d = ((size_t)blockIdx.z * Rp) << cshift;
    int total = Rp << cshift;
    for (int i = blockIdx.x * blockDim.x + threadIdx.x; i < total; i += gridDim.x * blockDim.x) {
        int r = i >> cshift, c = i & (Cp - 1);
        float v = (r < R && c < C) ? src[base_s + (size_t)r * C + c] : 0.0f;
        dst[base_d + i] = (half_t)v;
    }
}

// ---------------- GEMM ----------------
// MODE 0: dense   Y[M,Npad] = act(A[M,K] @ W[Npad,K]^T + bias)
// MODE 1: expand  (per-bucket z): A = xh rows of segment, K = d_ka[z], W = Win_h[z]
// MODE 2: contract(per-bucket z): fp32 scatter-store to d_out via perm, N tiles cut at s_z
template <int MODE, bool RELU>
__global__ __launch_bounds__(256)
void gemm_k(const half_t* __restrict__ Abase, const half_t* __restrict__ Wbase,
            const float* __restrict__ biasbase, half_t* __restrict__ Obase,
            float* __restrict__ out32, const int* __restrict__ meta,
            const int* __restrict__ perm, int Kdense, int Npad, int Nreal) {
    const int tid  = threadIdx.x;
    const int lane = tid & 63;
    const int wave = tid >> 6;
    const int mtile = blockIdx.x, ntile = blockIdx.y;

    int K, ld, rowbase, cnt = 0;
    const half_t* A;
    const half_t* W;
    const float* bias;
    if (MODE == 0) {
        K = Kdense; ld = Kdense;
        rowbase = mtile * 128;
        A = Abase + (size_t)rowbase * ld;
        W = Wbase + (size_t)ntile * 128 * ld;
        bias = biasbase;
    } else {
        int kb = blockIdx.z;
        cnt = meta[kb];
        int cnt_pad = (cnt + 127) & ~127;
        if (mtile * 128 >= cnt_pad) return;
        if (MODE == 2 && ntile * 128 >= d_sizes[kb]) return;
        ld = BASEP;
        K = (MODE == 1) ? d_ka[kb] : BASEP;
        rowbase = meta[5 + kb] + mtile * 128;
        A = Abase + (size_t)rowbase * BASEP;
        W = Wbase + (size_t)kb * BASEP * BASEP + (size_t)ntile * 128 * BASEP;
        bias = biasbase + kb * BASE;
    }

    __shared__ __align__(16) half_t As[128 * 32];
    __shared__ __align__(16) half_t Bs[128 * 32];

    f32x4 acc[4][4];
#pragma unroll
    for (int m = 0; m < 4; m++)
#pragma unroll
        for (int n = 0; n < 4; n++)
            acc[m][n] = (f32x4){0.f, 0.f, 0.f, 0.f};

    const int wr = (wave >> 1) * 64;   // wave's row quadrant
    const int wc = (wave & 1) * 64;    // wave's col quadrant
    const int fr = lane & 15;
    const int kc = lane >> 4;          // k-chunk 0..3
    const int wbase = tid & ~63;       // linear idx of lane0 of this wave

    for (int k0 = 0; k0 < K; k0 += 32) {
#pragma unroll
        for (int i = 0; i < 2; i++) {
            int idx = i * 256 + tid;
            int row = idx >> 2, ch = idx & 3;
            const half_t* ga = A + (size_t)row * ld + (k0 + ch * 8);
            const half_t* gb = W + (size_t)row * ld + (k0 + ch * 8);
            half_t* la = As + (size_t)(i * 256 + wbase) * 8;
            half_t* lb = Bs + (size_t)(i * 256 + wbase) * 8;
            __builtin_amdgcn_global_load_lds((__attribute__((address_space(1))) void*)(ga),
                                             (__attribute__((address_space(3))) void*)(la), 16, 0, 0);
            __builtin_amdgcn_global_load_lds((__attribute__((address_space(1))) void*)(gb),
                                             (__attribute__((address_space(3))) void*)(lb), 16, 0, 0);
        }
        __syncthreads();   // drains vmcnt before barrier (compiler-inserted)

        half8 af[4], bf[4];
#pragma unroll
        for (int m = 0; m < 4; m++)
            af[m] = *reinterpret_cast<const half8*>(&As[(wr + m * 16 + fr) * 32 + kc * 8]);
#pragma unroll
        for (int n = 0; n < 4; n++)
            bf[n] = *reinterpret_cast<const half8*>(&Bs[(wc + n * 16 + fr) * 32 + kc * 8]);
#pragma unroll
        for (int m = 0; m < 4; m++)
#pragma unroll
            for (int n = 0; n < 4; n++)
                acc[m][n] = __builtin_amdgcn_mfma_f32_16x16x32_f16(af[m], bf[n], acc[m][n], 0, 0, 0);
        __syncthreads();   // protect LDS from next iteration's staging
    }

    // epilogue: D row = (lane>>4)*4 + j, col = lane&15  (m89-verified layout)
    float bv[4];
#pragma unroll
    for (int n = 0; n < 4; n++) {
        int col = ntile * 128 + wc + n * 16 + fr;
        bv[n] = (col < Nreal) ? bias[col] : 0.0f;
    }
#pragma unroll
    for (int m = 0; m < 4; m++) {
#pragma unroll
        for (int j = 0; j < 4; j++) {
            int r = wr + m * 16 + kc * 4 + j;
#pragma unroll
            for (int n = 0; n < 4; n++) {
                float v = acc[m][n][j] + bv[n];
                if (RELU) v = fmaxf(v, 0.0f);
                int c = wc + n * 16 + fr;
                if (MODE == 2) {
                    if (mtile * 128 + r < cnt) {
                        int col = ntile * 128 + c;
                        if (col < BASE) {
                            int orig = perm[rowbase + r];
                            out32[(size_t)orig * BASE + col] = v;
                        }
                    }
                } else {
                    Obase[(size_t)(rowbase + r) * Npad + ntile * 128 + c] = (half_t)v;
                }
            }
        }
    }
}

// ---------------- launch ----------------
extern "C" void kernel_launch(void* const* d_in, const int* in_sizes, int n_in,
                              void* d_out, int out_size, void* d_ws, size_t ws_size,
                              hipStream_t stream) {
    (void)in_sizes; (void)n_in;
    if (ws_size < WS_NEED) return;  // workspace too small: fail loudly via wrong output

    const float* x    = (const float*)d_in[0];
    const int*   seq  = (const int*)d_in[1];
    const float* Win  = (const float*)d_in[2];
    const float* bin_ = (const float*)d_in[3];
    const float* Wout = (const float*)d_in[4];
    const float* bout = (const float*)d_in[5];
    const float* We1  = (const float*)d_in[6];  const float* be1 = (const float*)d_in[7];
    const float* We2  = (const float*)d_in[8];  const float* be2 = (const float*)d_in[9];
    const float* We3  = (const float*)d_in[10]; const float* be3 = (const float*)d_in[11];
    const float* Wd1  = (const float*)d_in[12]; const float* bd1 = (const float*)d_in[13];
    const float* Wd2  = (const float*)d_in[14]; const float* bd2 = (const float*)d_in[15];
    const float* Wd3  = (const float*)d_in[16]; const float* bd3 = (const float*)d_in[17];

    char* ws = (char*)d_ws;
    int*    meta   = (int*)(ws + OFF_META);
    int*    perm   = (int*)(ws + OFF_PERM);
    int*    rankb  = (int*)(ws + OFF_RANK);
    int*    pos    = (int*)(ws + OFF_POS);
    int*    blkt   = (int*)(ws + OFF_BLKT);
    int*    blkb   = (int*)(ws + OFF_BLKB);
    half_t* xh   = (half_t*)(ws + OFF_XH);
    half_t* E    = (half_t*)(ws + OFF_E);
    half_t* B512 = (half_t*)(ws + OFF_B512);
    half_t* C256 = (half_t*)(ws + OFF_C256);
    half_t* D128 = (half_t*)(ws + OFF_D128);
    half_t* winh = (half_t*)(ws + OFF_WIN);
    half_t* wouth= (half_t*)(ws + OFF_WOUT);
    half_t* we1h = (half_t*)(ws + OFF_WE1);
    half_t* we2h = (half_t*)(ws + OFF_WE2);
    half_t* we3h = (half_t*)(ws + OFF_WE3);
    half_t* wd1h = (half_t*)(ws + OFF_WD1);
    half_t* wd2h = (half_t*)(ws + OFF_WD2);
    half_t* wd3h = (half_t*)(ws + OFF_WD3);
    float*  out  = (float*)d_out;

    hipMemsetAsync(d_out, 0, (size_t)out_size * sizeof(float), stream);

    // deterministic bucket permutation (no atomics)
    rank_kernel<<<NBLK, 256, 0, stream>>>(seq, rankb, blkt);
    base_kernel<<<1, 64, 0, stream>>>(blkt, meta, blkb);
    finalize_kernel<<<NBLK, 256, 0, stream>>>(seq, rankb, blkb, perm, pos);
    zero_xh_pad<<<dim3(128, NB), 256, 0, stream>>>(meta, xh);
    copy_convert_kernel<<<2048, 256, 0, stream>>>(x, pos, xh);

    conv_pad<<<dim3(512, 1, NB), 256, 0, stream>>>(Win,  winh, 1008, 1008, 1024, 10);
    conv_pad<<<dim3(512, 1, NB), 256, 0, stream>>>(Wout, wouth, 1008, 1008, 1024, 10);
    conv_pad<<<dim3(512, 1, 1), 256, 0, stream>>>(We1, we1h,  512, 1008,  512, 10);
    conv_pad<<<dim3(128, 1, 1), 256, 0, stream>>>(We2, we2h,  256,  512,  256,  9);
    conv_pad<<<dim3(64, 1, 1),  256, 0, stream>>>(We3, we3h,  128,  256,  128,  8);
    conv_pad<<<dim3(64, 1, 1),  256, 0, stream>>>(Wd1, wd1h,  256,  128,  256,  7);
    conv_pad<<<dim3(128, 1, 1), 256, 0, stream>>>(Wd2, wd2h,  512,  256,  512,  8);
    conv_pad<<<dim3(512, 1, 1), 256, 0, stream>>>(Wd3, wd3h, 1008,  512, 1024,  9);

    // expand: per-bucket K-trimmed GEMM, xh -> E [.,1024]
    gemm_k<1, false><<<dim3(128, 8, NB), 256, 0, stream>>>(xh, winh, bin_, E, nullptr, meta, perm, 0, 1024, 1008);
    // encoder
    gemm_k<0, true ><<<dim3(MT_DENSE, 4), 256, 0, stream>>>(E,    we1h, be1, B512, nullptr, meta, perm, 1024, 512, 512);
    gemm_k<0, true ><<<dim3(MT_DENSE, 2), 256, 0, stream>>>(B512, we2h, be2, C256, nullptr, meta, perm,  512, 256, 256);
    gemm_k<0, false><<<dim3(MT_DENSE, 1), 256, 0, stream>>>(C256, we3h, be3, D128, nullptr, meta, perm,  256, 128, 128);
    // decoder
    gemm_k<0, true ><<<dim3(MT_DENSE, 2), 256, 0, stream>>>(D128, wd1h, bd1, C256, nullptr, meta, perm,  128, 256, 256);
    gemm_k<0, true ><<<dim3(MT_DENSE, 4), 256, 0, stream>>>(C256, wd2h, bd2, B512, nullptr, meta, perm,  256, 512, 512);
    gemm_k<0, false><<<dim3(MT_DENSE, 8), 256, 0, stream>>>(B512, wd3h, bd3, E,    nullptr, meta, perm,  512, 1024, 1008);
    // contract: per-bucket N-tile-cut GEMM, scatter fp32 rows into pre-zeroed d_out
    gemm_k<2, false><<<dim3(128, 8, NB), 256, 0, stream>>>(E, wouth, bout, nullptr, out, meta, perm, 1024, 1024, 1008);
}

// Round 5
// 428.384 us; speedup vs baseline: 2.9925x; 1.0401x over previous
//
#include <hip/hip_runtime.h>

typedef _Float16 half_t;
typedef __attribute__((ext_vector_type(4))) _Float16 half4;
typedef __attribute__((ext_vector_type(8))) _Float16 half8;
typedef __attribute__((ext_vector_type(4))) float f32x4;

#define BATCH  16384
#define BASE   1008
#define BASEP  1024
#define NB     5
#define ROWS_P 17024      // 16384 + 5*128 (segment alignment slack)
#define MT_DENSE 133      // ROWS_P / 128
#define NBLK   64         // BATCH / 256

__constant__ int d_sizes[NB] = {36, 72, 144, 288, 1008};
__constant__ int d_ka[NB]    = {64, 96, 160, 288, 1024};   // align32(s)

__device__ __forceinline__ int bucket_of(int s) {
    return (s == 36) ? 0 : (s == 72) ? 1 : (s == 144) ? 2 : (s == 288) ? 3 : 4;
}

// ---------------- ws layout (bytes) ----------------
// meta: [0..4]=cnt, [5..9]=seg_start (128-aligned)
constexpr size_t OFF_META = 0;                                   // 256 B reserved
constexpr size_t OFF_PERM = 256;                                 // ROWS_P ints
constexpr size_t OFF_RANK = OFF_PERM + (size_t)ROWS_P * 4;       // BATCH ints
constexpr size_t OFF_POS  = OFF_RANK + (size_t)BATCH * 4;        // BATCH ints
constexpr size_t OFF_BLKT = OFF_POS  + (size_t)BATCH * 4;        // NBLK*NB ints
constexpr size_t OFF_BLKB = OFF_BLKT + (size_t)NBLK * NB * 4;    // NBLK*NB ints
constexpr size_t OFF_XH   = (OFF_BLKB + (size_t)NBLK * NB * 4 + 255) & ~(size_t)255;
constexpr size_t SZ1024   = (size_t)ROWS_P * 1024 * 2;
constexpr size_t OFF_E    = OFF_XH + SZ1024;                     // fp16 [ROWS_P][1024]
constexpr size_t OFF_B512 = OFF_E + SZ1024;                      // fp16 [ROWS_P][512]
constexpr size_t OFF_C256 = OFF_B512 + (size_t)ROWS_P * 512 * 2; // fp16 [ROWS_P][256]
constexpr size_t OFF_D128 = OFF_C256 + (size_t)ROWS_P * 256 * 2; // fp16 [ROWS_P][128]
constexpr size_t OFF_WIN  = OFF_D128 + (size_t)ROWS_P * 128 * 2; // fp16 [5][1024][1024]
constexpr size_t OFF_WOUT = OFF_WIN  + (size_t)NB * 1024 * 1024 * 2;
constexpr size_t OFF_WE1  = OFF_WOUT + (size_t)NB * 1024 * 1024 * 2; // [512][1024]
constexpr size_t OFF_WE2  = OFF_WE1 + (size_t)512 * 1024 * 2;        // [256][512]
constexpr size_t OFF_WE3  = OFF_WE2 + (size_t)256 * 512 * 2;         // [128][256]
constexpr size_t OFF_WD1  = OFF_WE3 + (size_t)128 * 256 * 2;         // [256][128]
constexpr size_t OFF_WD2  = OFF_WD1 + (size_t)256 * 128 * 2;         // [512][256]
constexpr size_t OFF_WD3  = OFF_WD2 + (size_t)512 * 256 * 2;         // [1024][512]
constexpr size_t WS_NEED  = OFF_WD3 + (size_t)1024 * 512 * 2;        // ~118.4 MiB

// ---------------- deterministic permutation (no atomics anywhere) ----------------
__global__ void rank_kernel(const int* __restrict__ seq, int* __restrict__ rankb,
                            int* __restrict__ blk_tot) {
    __shared__ int wcnt[4][NB];
    __shared__ int wbase[4][NB];
    const int tid = threadIdx.x, lane = tid & 63, wave = tid >> 6;
    const int b = blockIdx.x * 256 + tid;
    const int k = bucket_of(seq[b]);
    unsigned long long same = 0;
#pragma unroll
    for (int kk = 0; kk < NB; kk++) {
        unsigned long long mk = __ballot(k == kk);
        if (lane == 0) wcnt[wave][kk] = __popcll(mk);
        if (k == kk) same = mk;
    }
    const int lr = __popcll(same & ((1ull << lane) - 1ull));
    __syncthreads();
    if (tid < NB) {                       // tid = bucket index
        int s = 0;
#pragma unroll
        for (int w = 0; w < 4; w++) { wbase[w][tid] = s; s += wcnt[w][tid]; }
        blk_tot[blockIdx.x * NB + tid] = s;
    }
    __syncthreads();
    rankb[b] = wbase[wave][k] + lr;
}

__global__ void base_kernel(const int* __restrict__ blk_tot, int* __restrict__ meta,
                            int* __restrict__ blkbase) {
    __shared__ int tot[NB], seg[NB];
    const int tid = threadIdx.x;
    if (tid < NB) {
        int s = 0;
        for (int blk = 0; blk < NBLK; blk++) {
            blkbase[blk * NB + tid] = s;
            s += blk_tot[blk * NB + tid];
        }
        tot[tid] = s;
    }
    __syncthreads();
    if (tid == 0) {
        int off = 0;
        for (int kk = 0; kk < NB; kk++) {
            seg[kk] = off;
            meta[kk] = tot[kk];
            meta[5 + kk] = off;
            off += (tot[kk] + 127) & ~127;
        }
    }
    __syncthreads();
    if (tid < NB)
        for (int blk = 0; blk < NBLK; blk++) blkbase[blk * NB + tid] += seg[tid];
}

__global__ void finalize_kernel(const int* __restrict__ seq, const int* __restrict__ rankb,
                                const int* __restrict__ blkbase, int* __restrict__ perm,
                                int* __restrict__ pos) {
    const int b = blockIdx.x * 256 + threadIdx.x;
    const int k = bucket_of(seq[b]);
    const int p = blkbase[blockIdx.x * NB + k] + rankb[b];
    perm[p] = b;
    pos[b] = p;
}

// Zero xh segment-padding rows so no GEMM input is ever read-before-write.
__global__ void zero_xh_pad(const int* __restrict__ meta, half_t* __restrict__ xh) {
    const int kb = blockIdx.y;
    const int cnt = meta[kb];
    const int cnt_pad = (cnt + 127) & ~127;
    const int r = cnt + blockIdx.x;
    if (r >= cnt_pad) return;
    const int row = meta[5 + kb] + r;
    half4 z; z.x = z.y = z.z = z.w = (half_t)0.0f;
    *reinterpret_cast<half4*>(xh + (size_t)row * BASEP + threadIdx.x * 4) = z;
}

// Pure coalesced convert+scatter: no atomics, no syncthreads.
__global__ void copy_convert_kernel(const float* __restrict__ x, const int* __restrict__ pos,
                                    half_t* __restrict__ xh) {
    for (int b = blockIdx.x; b < BATCH; b += gridDim.x) {
        int p = pos[b];
        int c = threadIdx.x * 4;  // 0..1020
        half4 o4;
        if (c < BASE) {
            float4 v = *reinterpret_cast<const float4*>(x + (size_t)b * BASE + c);
            o4.x = (half_t)v.x; o4.y = (half_t)v.y; o4.z = (half_t)v.z; o4.w = (half_t)v.w;
        } else {
            o4.x = o4.y = o4.z = o4.w = (half_t)0.0f;
        }
        *reinterpret_cast<half4*>(xh + (size_t)p * BASEP + c) = o4;
    }
}

// fp32 -> fp16 convert with zero padding.
// mode 0: full matrix.  mode 1 (Win): only cols < d_ka[z] are ever read by the
// expand GEMM -> skip the rest.  mode 2 (Wout): only rows < align128(s_z) are
// ever read by the contract GEMM -> iterate only those.
__global__ void conv_pad(const float* __restrict__ src, half_t* __restrict__ dst,
                         int R, int C, int Rp, int cshift, int mode) {
    int Cp = 1 << cshift;
    int z = blockIdx.z;
    int climit = (mode == 1) ? d_ka[z] : Cp;
    int rlimit = (mode == 2) ? ((d_sizes[z] + 127) & ~127) : Rp;
    size_t base_s = (size_t)z * R * C;
    size_t base_d = ((size_t)z * Rp) << cshift;
    int total = rlimit << cshift;
    for (int i = blockIdx.x * blockDim.x + threadIdx.x; i < total; i += gridDim.x * blockDim.x) {
        int r = i >> cshift, c = i & (Cp - 1);
        if (c >= climit) continue;
        float v = (r < R && c < C) ? src[base_s + (size_t)r * C + c] : 0.0f;
        dst[base_d + i] = (half_t)v;
    }
}

// ---------------- GEMM ----------------
// 128x128 tile, BK=32, 4 waves, double-buffered LDS, ONE barrier per K-step:
//   STAGE(next tile -> buf^1)  [global_load_lds, in flight across compute]
//   ds_read buf -> frags; 16 MFMA/wave
//   __syncthreads()            [drains vmcnt(0): next tile landed; swap]
// MODE 0: dense   MODE 1: expand (per-bucket K=ka)   MODE 2: contract (scatter fp32)
template <int MODE, bool RELU>
__global__ __launch_bounds__(256)
void gemm_k(const half_t* __restrict__ Abase, const half_t* __restrict__ Wbase,
            const float* __restrict__ biasbase, half_t* __restrict__ Obase,
            float* __restrict__ out32, const int* __restrict__ meta,
            const int* __restrict__ perm, int Kdense, int Npad, int Nreal) {
    const int tid  = threadIdx.x;
    const int lane = tid & 63;
    const int wave = tid >> 6;
    const int mtile = blockIdx.x, ntile = blockIdx.y;

    int K, ld, rowbase, cnt = 0;
    const half_t* A;
    const half_t* W;
    const float* bias;
    if (MODE == 0) {
        K = Kdense; ld = Kdense;
        rowbase = mtile * 128;
        A = Abase + (size_t)rowbase * ld;
        W = Wbase + (size_t)ntile * 128 * ld;
        bias = biasbase;
    } else {
        int kb = blockIdx.z;
        cnt = meta[kb];
        int cnt_pad = (cnt + 127) & ~127;
        if (mtile * 128 >= cnt_pad) return;
        if (MODE == 2 && ntile * 128 >= d_sizes[kb]) return;
        ld = BASEP;
        K = (MODE == 1) ? d_ka[kb] : BASEP;
        rowbase = meta[5 + kb] + mtile * 128;
        A = Abase + (size_t)rowbase * BASEP;
        W = Wbase + (size_t)kb * BASEP * BASEP + (size_t)ntile * 128 * BASEP;
        bias = biasbase + kb * BASE;
    }

    __shared__ __align__(16) half_t As[2][128 * 32];
    __shared__ __align__(16) half_t Bs[2][128 * 32];

    f32x4 acc[4][4];
#pragma unroll
    for (int m = 0; m < 4; m++)
#pragma unroll
        for (int n = 0; n < 4; n++)
            acc[m][n] = (f32x4){0.f, 0.f, 0.f, 0.f};

    const int wr = (wave >> 1) * 64;   // wave's row quadrant
    const int wc = (wave & 1) * 64;    // wave's col quadrant
    const int fr = lane & 15;
    const int kc = lane >> 4;          // k-chunk 0..3
    const int wbase = tid & ~63;       // linear idx of lane0 of this wave

#define STAGE(buf, kk)                                                                        \
    do {                                                                                      \
        _Pragma("unroll")                                                                     \
        for (int i_ = 0; i_ < 2; i_++) {                                                      \
            int idx_ = i_ * 256 + tid;                                                        \
            int row_ = idx_ >> 2, ch_ = idx_ & 3;                                             \
            const half_t* ga_ = A + (size_t)row_ * ld + ((kk) + ch_ * 8);                     \
            const half_t* gb_ = W + (size_t)row_ * ld + ((kk) + ch_ * 8);                     \
            half_t* la_ = &As[buf][(size_t)(i_ * 256 + wbase) * 8];                           \
            half_t* lb_ = &Bs[buf][(size_t)(i_ * 256 + wbase) * 8];                           \
            __builtin_amdgcn_global_load_lds((__attribute__((address_space(1))) void*)(ga_),  \
                                             (__attribute__((address_space(3))) void*)(la_),  \
                                             16, 0, 0);                                       \
            __builtin_amdgcn_global_load_lds((__attribute__((address_space(1))) void*)(gb_),  \
                                             (__attribute__((address_space(3))) void*)(lb_),  \
                                             16, 0, 0);                                       \
        }                                                                                     \
    } while (0)

    STAGE(0, 0);
    __syncthreads();          // buf0 landed (vmcnt drained by syncthreads)

    int cur = 0;
    for (int k0 = 0; k0 < K; k0 += 32) {
        if (k0 + 32 < K) STAGE(cur ^ 1, k0 + 32);   // prefetch rides under compute

        half8 af[4], bf[4];
#pragma unroll
        for (int m = 0; m < 4; m++)
            af[m] = *reinterpret_cast<const half8*>(&As[cur][(wr + m * 16 + fr) * 32 + kc * 8]);
#pragma unroll
        for (int n = 0; n < 4; n++)
            bf[n] = *reinterpret_cast<const half8*>(&Bs[cur][(wc + n * 16 + fr) * 32 + kc * 8]);
#pragma unroll
        for (int m = 0; m < 4; m++)
#pragma unroll
            for (int n = 0; n < 4; n++)
                acc[m][n] = __builtin_amdgcn_mfma_f32_16x16x32_f16(af[m], bf[n], acc[m][n], 0, 0, 0);

        __syncthreads();      // drains vmcnt(0): prefetched tile ready; LDS reads done
        cur ^= 1;
    }
#undef STAGE

    // epilogue: D row = (lane>>4)*4 + j, col = lane&15  (m89-verified layout)
    float bv[4];
#pragma unroll
    for (int n = 0; n < 4; n++) {
        int col = ntile * 128 + wc + n * 16 + fr;
        bv[n] = (col < Nreal) ? bias[col] : 0.0f;
    }
#pragma unroll
    for (int m = 0; m < 4; m++) {
#pragma unroll
        for (int j = 0; j < 4; j++) {
            int r = wr + m * 16 + kc * 4 + j;
#pragma unroll
            for (int n = 0; n < 4; n++) {
                float v = acc[m][n][j] + bv[n];
                if (RELU) v = fmaxf(v, 0.0f);
                int c = wc + n * 16 + fr;
                if (MODE == 2) {
                    if (mtile * 128 + r < cnt) {
                        int col = ntile * 128 + c;
                        if (col < BASE) {
                            int orig = perm[rowbase + r];
                            out32[(size_t)orig * BASE + col] = v;
                        }
                    }
                } else {
                    Obase[(size_t)(rowbase + r) * Npad + ntile * 128 + c] = (half_t)v;
                }
            }
        }
    }
}

// ---------------- launch ----------------
extern "C" void kernel_launch(void* const* d_in, const int* in_sizes, int n_in,
                              void* d_out, int out_size, void* d_ws, size_t ws_size,
                              hipStream_t stream) {
    (void)in_sizes; (void)n_in;
    if (ws_size < WS_NEED) return;

    const float* x    = (const float*)d_in[0];
    const int*   seq  = (const int*)d_in[1];
    const float* Win  = (const float*)d_in[2];
    const float* bin_ = (const float*)d_in[3];
    const float* Wout = (const float*)d_in[4];
    const float* bout = (const float*)d_in[5];
    const float* We1  = (const float*)d_in[6];  const float* be1 = (const float*)d_in[7];
    const float* We2  = (const float*)d_in[8];  const float* be2 = (const float*)d_in[9];
    const float* We3  = (const float*)d_in[10]; const float* be3 = (const float*)d_in[11];
    const float* Wd1  = (const float*)d_in[12]; const float* bd1 = (const float*)d_in[13];
    const float* Wd2  = (const float*)d_in[14]; const float* bd2 = (const float*)d_in[15];
    const float* Wd3  = (const float*)d_in[16]; const float* bd3 = (const float*)d_in[17];

    char* ws = (char*)d_ws;
    int*    meta   = (int*)(ws + OFF_META);
    int*    perm   = (int*)(ws + OFF_PERM);
    int*    rankb  = (int*)(ws + OFF_RANK);
    int*    pos    = (int*)(ws + OFF_POS);
    int*    blkt   = (int*)(ws + OFF_BLKT);
    int*    blkb   = (int*)(ws + OFF_BLKB);
    half_t* xh   = (half_t*)(ws + OFF_XH);
    half_t* E    = (half_t*)(ws + OFF_E);
    half_t* B512 = (half_t*)(ws + OFF_B512);
    half_t* C256 = (half_t*)(ws + OFF_C256);
    half_t* D128 = (half_t*)(ws + OFF_D128);
    half_t* winh = (half_t*)(ws + OFF_WIN);
    half_t* wouth= (half_t*)(ws + OFF_WOUT);
    half_t* we1h = (half_t*)(ws + OFF_WE1);
    half_t* we2h = (half_t*)(ws + OFF_WE2);
    half_t* we3h = (half_t*)(ws + OFF_WE3);
    half_t* wd1h = (half_t*)(ws + OFF_WD1);
    half_t* wd2h = (half_t*)(ws + OFF_WD2);
    half_t* wd3h = (half_t*)(ws + OFF_WD3);
    float*  out  = (float*)d_out;

    hipMemsetAsync(d_out, 0, (size_t)out_size * sizeof(float), stream);

    // deterministic bucket permutation (no atomics)
    rank_kernel<<<NBLK, 256, 0, stream>>>(seq, rankb, blkt);
    base_kernel<<<1, 64, 0, stream>>>(blkt, meta, blkb);
    finalize_kernel<<<NBLK, 256, 0, stream>>>(seq, rankb, blkb, perm, pos);
    zero_xh_pad<<<dim3(128, NB), 256, 0, stream>>>(meta, xh);
    copy_convert_kernel<<<2048, 256, 0, stream>>>(x, pos, xh);

    conv_pad<<<dim3(512, 1, NB), 256, 0, stream>>>(Win,  winh, 1008, 1008, 1024, 10, 1);
    conv_pad<<<dim3(512, 1, NB), 256, 0, stream>>>(Wout, wouth, 1008, 1008, 1024, 10, 2);
    conv_pad<<<dim3(512, 1, 1), 256, 0, stream>>>(We1, we1h,  512, 1008,  512, 10, 0);
    conv_pad<<<dim3(128, 1, 1), 256, 0, stream>>>(We2, we2h,  256,  512,  256,  9, 0);
    conv_pad<<<dim3(64, 1, 1),  256, 0, stream>>>(We3, we3h,  128,  256,  128,  8, 0);
    conv_pad<<<dim3(64, 1, 1),  256, 0, stream>>>(Wd1, wd1h,  256,  128,  256,  7, 0);
    conv_pad<<<dim3(128, 1, 1), 256, 0, stream>>>(Wd2, wd2h,  512,  256,  512,  8, 0);
    conv_pad<<<dim3(512, 1, 1), 256, 0, stream>>>(Wd3, wd3h, 1008,  512, 1024,  9, 0);

    // expand: per-bucket K-trimmed GEMM, xh -> E [.,1024]
    gemm_k<1, false><<<dim3(128, 8, NB), 256, 0, stream>>>(xh, winh, bin_, E, nullptr, meta, perm, 0, 1024, 1008);
    // encoder
    gemm_k<0, true ><<<dim3(MT_DENSE, 4), 256, 0, stream>>>(E,    we1h, be1, B512, nullptr, meta, perm, 1024, 512, 512);
    gemm_k<0, true ><<<dim3(MT_DENSE, 2), 256, 0, stream>>>(B512, we2h, be2, C256, nullptr, meta, perm,  512, 256, 256);
    gemm_k<0, false><<<dim3(MT_DENSE, 1), 256, 0, stream>>>(C256, we3h, be3, D128, nullptr, meta, perm,  256, 128, 128);
    // decoder
    gemm_k<0, true ><<<dim3(MT_DENSE, 2), 256, 0, stream>>>(D128, wd1h, bd1, C256, nullptr, meta, perm,  128, 256, 256);
    gemm_k<0, true ><<<dim3(MT_DENSE, 4), 256, 0, stream>>>(C256, wd2h, bd2, B512, nullptr, meta, perm,  256, 512, 512);
    gemm_k<0, false><<<dim3(MT_DENSE, 8), 256, 0, stream>>>(B512, wd3h, bd3, E,    nullptr, meta, perm,  512, 1024, 1008);
    // contract: per-bucket N-tile-cut GEMM, scatter fp32 rows into pre-zeroed d_out
    gemm_k<2, false><<<dim3(128, 8, NB), 256, 0, stream>>>(E, wouth, bout, nullptr, out, meta, perm, 1024, 1024, 1008);
}

// Round 6
// 415.105 us; speedup vs baseline: 3.0882x; 1.0320x over previous
//
#include <hip/hip_runtime.h>

typedef _Float16 half_t;
typedef __attribute__((ext_vector_type(4))) _Float16 half4;
typedef __attribute__((ext_vector_type(8))) _Float16 half8;
typedef __attribute__((ext_vector_type(4))) float f32x4;

#define BATCH  16384
#define BASE   1008
#define BASEP  1024
#define NB     5
#define ROWS_P 17024      // 16384 + 5*128 (segment alignment slack)
#define MT_DENSE 133      // ROWS_P / 128
#define NBLK   64         // BATCH / 256

__constant__ int d_sizes[NB] = {36, 72, 144, 288, 1008};
__constant__ int d_ka[NB]    = {64, 96, 160, 288, 1024};   // align32(s)

__device__ __forceinline__ int bucket_of(int s) {
    return (s == 36) ? 0 : (s == 72) ? 1 : (s == 144) ? 2 : (s == 288) ? 3 : 4;
}

// ---------------- ws layout (bytes) ----------------
// meta: [0..4]=cnt, [5..9]=seg_start (128-aligned)
constexpr size_t OFF_META = 0;                                   // 256 B reserved
constexpr size_t OFF_PERM = 256;                                 // ROWS_P ints
constexpr size_t OFF_RANK = OFF_PERM + (size_t)ROWS_P * 4;       // BATCH ints
constexpr size_t OFF_POS  = OFF_RANK + (size_t)BATCH * 4;        // BATCH ints
constexpr size_t OFF_BLKT = OFF_POS  + (size_t)BATCH * 4;        // NBLK*NB ints
constexpr size_t OFF_BLKB = OFF_BLKT + (size_t)NBLK * NB * 4;    // NBLK*NB ints
constexpr size_t OFF_XH   = (OFF_BLKB + (size_t)NBLK * NB * 4 + 255) & ~(size_t)255;
constexpr size_t SZ1024   = (size_t)ROWS_P * 1024 * 2;
constexpr size_t OFF_E    = OFF_XH + SZ1024;                     // fp16 [ROWS_P][1024]
constexpr size_t OFF_B512 = OFF_E + SZ1024;                      // fp16 [ROWS_P][512]
constexpr size_t OFF_C256 = OFF_B512 + (size_t)ROWS_P * 512 * 2; // fp16 [ROWS_P][256]
constexpr size_t OFF_D128 = OFF_C256 + (size_t)ROWS_P * 256 * 2; // fp16 [ROWS_P][128]
constexpr size_t OFF_WIN  = OFF_D128 + (size_t)ROWS_P * 128 * 2; // fp16 [5][1024][1024]
constexpr size_t OFF_WOUT = OFF_WIN  + (size_t)NB * 1024 * 1024 * 2;
constexpr size_t OFF_WE1  = OFF_WOUT + (size_t)NB * 1024 * 1024 * 2; // [512][1024]
constexpr size_t OFF_WE2  = OFF_WE1 + (size_t)512 * 1024 * 2;        // [256][512]
constexpr size_t OFF_WE3  = OFF_WE2 + (size_t)256 * 512 * 2;         // [128][256]
constexpr size_t OFF_WD1  = OFF_WE3 + (size_t)128 * 256 * 2;         // [256][128]
constexpr size_t OFF_WD2  = OFF_WD1 + (size_t)256 * 128 * 2;         // [512][256]
constexpr size_t OFF_WD3  = OFF_WD2 + (size_t)512 * 256 * 2;         // [1024][512]
constexpr size_t WS_NEED  = OFF_WD3 + (size_t)1024 * 512 * 2;        // ~118.4 MiB

// ---------------- deterministic permutation (no atomics anywhere) ----------------
__global__ void rank_kernel(const int* __restrict__ seq, int* __restrict__ rankb,
                            int* __restrict__ blk_tot) {
    __shared__ int wcnt[4][NB];
    __shared__ int wbase[4][NB];
    const int tid = threadIdx.x, lane = tid & 63, wave = tid >> 6;
    const int b = blockIdx.x * 256 + tid;
    const int k = bucket_of(seq[b]);
    unsigned long long same = 0;
#pragma unroll
    for (int kk = 0; kk < NB; kk++) {
        unsigned long long mk = __ballot(k == kk);
        if (lane == 0) wcnt[wave][kk] = __popcll(mk);
        if (k == kk) same = mk;
    }
    const int lr = __popcll(same & ((1ull << lane) - 1ull));
    __syncthreads();
    if (tid < NB) {                       // tid = bucket index
        int s = 0;
#pragma unroll
        for (int w = 0; w < 4; w++) { wbase[w][tid] = s; s += wcnt[w][tid]; }
        blk_tot[blockIdx.x * NB + tid] = s;
    }
    __syncthreads();
    rankb[b] = wbase[wave][k] + lr;
}

__global__ void base_kernel(const int* __restrict__ blk_tot, int* __restrict__ meta,
                            int* __restrict__ blkbase) {
    __shared__ int tot[NB], seg[NB];
    const int tid = threadIdx.x;
    if (tid < NB) {
        int s = 0;
        for (int blk = 0; blk < NBLK; blk++) {
            blkbase[blk * NB + tid] = s;
            s += blk_tot[blk * NB + tid];
        }
        tot[tid] = s;
    }
    __syncthreads();
    if (tid == 0) {
        int off = 0;
        for (int kk = 0; kk < NB; kk++) {
            seg[kk] = off;
            meta[kk] = tot[kk];
            meta[5 + kk] = off;
            off += (tot[kk] + 127) & ~127;
        }
    }
    __syncthreads();
    if (tid < NB)
        for (int blk = 0; blk < NBLK; blk++) blkbase[blk * NB + tid] += seg[tid];
}

__global__ void finalize_kernel(const int* __restrict__ seq, const int* __restrict__ rankb,
                                const int* __restrict__ blkbase, int* __restrict__ perm,
                                int* __restrict__ pos) {
    const int b = blockIdx.x * 256 + threadIdx.x;
    const int k = bucket_of(seq[b]);
    const int p = blkbase[blockIdx.x * NB + k] + rankb[b];
    perm[p] = b;
    pos[b] = p;
}

// Zero xh segment-padding rows so no GEMM input is ever read-before-write.
__global__ void zero_xh_pad(const int* __restrict__ meta, half_t* __restrict__ xh) {
    const int kb = blockIdx.y;
    const int cnt = meta[kb];
    const int cnt_pad = (cnt + 127) & ~127;
    const int r = cnt + blockIdx.x;
    if (r >= cnt_pad) return;
    const int row = meta[5 + kb] + r;
    half4 z; z.x = z.y = z.z = z.w = (half_t)0.0f;
    *reinterpret_cast<half4*>(xh + (size_t)row * BASEP + threadIdx.x * 4) = z;
}

// Pure coalesced convert+scatter: no atomics, no syncthreads.
__global__ void copy_convert_kernel(const float* __restrict__ x, const int* __restrict__ pos,
                                    half_t* __restrict__ xh) {
    for (int b = blockIdx.x; b < BATCH; b += gridDim.x) {
        int p = pos[b];
        int c = threadIdx.x * 4;  // 0..1020
        half4 o4;
        if (c < BASE) {
            float4 v = *reinterpret_cast<const float4*>(x + (size_t)b * BASE + c);
            o4.x = (half_t)v.x; o4.y = (half_t)v.y; o4.z = (half_t)v.z; o4.w = (half_t)v.w;
        } else {
            o4.x = o4.y = o4.z = o4.w = (half_t)0.0f;
        }
        *reinterpret_cast<half4*>(xh + (size_t)p * BASEP + c) = o4;
    }
}

// fp32 -> fp16 convert with zero padding.
// mode 0: full matrix.  mode 1 (Win): only cols < d_ka[z] read by expand.
// mode 2 (Wout): only rows < align128(s_z) read by contract.
__global__ void conv_pad(const float* __restrict__ src, half_t* __restrict__ dst,
                         int R, int C, int Rp, int cshift, int mode) {
    int Cp = 1 << cshift;
    int z = blockIdx.z;
    int climit = (mode == 1) ? d_ka[z] : Cp;
    int rlimit = (mode == 2) ? ((d_sizes[z] + 127) & ~127) : Rp;
    size_t base_s = (size_t)z * R * C;
    size_t base_d = ((size_t)z * Rp) << cshift;
    int total = rlimit << cshift;
    for (int i = blockIdx.x * blockDim.x + threadIdx.x; i < total; i += gridDim.x * blockDim.x) {
        int r = i >> cshift, c = i & (Cp - 1);
        if (c >= climit) continue;
        float v = (r < R && c < C) ? src[base_s + (size_t)r * C + c] : 0.0f;
        dst[base_d + i] = (half_t)v;
    }
}

// ---------------- GEMM ----------------
// 128x128 tile, BK=32, 4 waves. 3-buffer LDS pipeline, depth-2 prefetch,
// counted vmcnt (T4), ONE raw s_barrier per K-step:
//   iter i: vmcnt(4) [tile i landed; tile i+1 still in flight] ; s_barrier ;
//           ds_read buf[i%3] ; 16 MFMA/wave ; STAGE(tile i+2 -> buf[(i+2)%3])
// Safety: buf[(i+2)%3] held tile i-1, whose reads completed before the iter-i
// barrier that every wave passed before this STAGE issues. Never vmcnt(0) in
// the main loop (only last iter).
template <int MODE, bool RELU>
__global__ __launch_bounds__(256)
void gemm_k(const half_t* __restrict__ Abase, const half_t* __restrict__ Wbase,
            const float* __restrict__ biasbase, half_t* __restrict__ Obase,
            float* __restrict__ out32, const int* __restrict__ meta,
            const int* __restrict__ perm, int Kdense, int Npad, int Nreal) {
    const int tid  = threadIdx.x;
    const int lane = tid & 63;
    const int wave = tid >> 6;
    const int mtile = blockIdx.x, ntile = blockIdx.y;

    int K, ld, rowbase, cnt = 0;
    const half_t* A;
    const half_t* W;
    const float* bias;
    if (MODE == 0) {
        K = Kdense; ld = Kdense;
        rowbase = mtile * 128;
        A = Abase + (size_t)rowbase * ld;
        W = Wbase + (size_t)ntile * 128 * ld;
        bias = biasbase;
    } else {
        int kb = blockIdx.z;
        cnt = meta[kb];
        int cnt_pad = (cnt + 127) & ~127;
        if (mtile * 128 >= cnt_pad) return;
        if (MODE == 2 && ntile * 128 >= d_sizes[kb]) return;
        ld = BASEP;
        K = (MODE == 1) ? d_ka[kb] : BASEP;
        rowbase = meta[5 + kb] + mtile * 128;
        A = Abase + (size_t)rowbase * BASEP;
        W = Wbase + (size_t)kb * BASEP * BASEP + (size_t)ntile * 128 * BASEP;
        bias = biasbase + kb * BASE;
    }

    __shared__ __align__(16) half_t As[3][128 * 32];
    __shared__ __align__(16) half_t Bs[3][128 * 32];

    f32x4 acc[4][4];
#pragma unroll
    for (int m = 0; m < 4; m++)
#pragma unroll
        for (int n = 0; n < 4; n++)
            acc[m][n] = (f32x4){0.f, 0.f, 0.f, 0.f};

    const int wr = (wave >> 1) * 64;   // wave's row quadrant
    const int wc = (wave & 1) * 64;    // wave's col quadrant
    const int fr = lane & 15;
    const int kc = lane >> 4;          // k-chunk 0..3
    const int wbase = tid & ~63;       // linear idx of lane0 of this wave

    // Each STAGE = exactly 4 global_load_lds instructions per wave (vmcnt +4).
#define STAGE(buf, kk)                                                                        \
    do {                                                                                      \
        _Pragma("unroll")                                                                     \
        for (int i_ = 0; i_ < 2; i_++) {                                                      \
            int idx_ = i_ * 256 + tid;                                                        \
            int row_ = idx_ >> 2, ch_ = idx_ & 3;                                             \
            const half_t* ga_ = A + (size_t)row_ * ld + ((kk) + ch_ * 8);                     \
            const half_t* gb_ = W + (size_t)row_ * ld + ((kk) + ch_ * 8);                     \
            half_t* la_ = &As[buf][(size_t)(i_ * 256 + wbase) * 8];                           \
            half_t* lb_ = &Bs[buf][(size_t)(i_ * 256 + wbase) * 8];                           \
            __builtin_amdgcn_global_load_lds((__attribute__((address_space(1))) void*)(ga_),  \
                                             (__attribute__((address_space(3))) void*)(la_),  \
                                             16, 0, 0);                                       \
            __builtin_amdgcn_global_load_lds((__attribute__((address_space(1))) void*)(gb_),  \
                                             (__attribute__((address_space(3))) void*)(lb_),  \
                                             16, 0, 0);                                       \
        }                                                                                     \
    } while (0)

    const int NI = K >> 5;             // K/32 iterations (K is a multiple of 32)
    STAGE(0, 0);
    if (NI > 1) STAGE(1, 32);

    int cur = 0;
    for (int i = 0; i < NI; i++) {
        // counted wait: my tile-i loads done (4 = tile i+1's loads may remain)
        if (i + 1 < NI) asm volatile("s_waitcnt vmcnt(4)" ::: "memory");
        else            asm volatile("s_waitcnt vmcnt(0)" ::: "memory");
        __builtin_amdgcn_s_barrier();          // all waves' tile-i loads landed
        asm volatile("" ::: "memory");         // pin LDS reads below the barrier

        half8 af[4], bf[4];
#pragma unroll
        for (int m = 0; m < 4; m++)
            af[m] = *reinterpret_cast<const half8*>(&As[cur][(wr + m * 16 + fr) * 32 + kc * 8]);
#pragma unroll
        for (int n = 0; n < 4; n++)
            bf[n] = *reinterpret_cast<const half8*>(&Bs[cur][(wc + n * 16 + fr) * 32 + kc * 8]);
#pragma unroll
        for (int m = 0; m < 4; m++)
#pragma unroll
            for (int n = 0; n < 4; n++)
                acc[m][n] = __builtin_amdgcn_mfma_f32_16x16x32_f16(af[m], bf[n], acc[m][n], 0, 0, 0);

        if (i + 2 < NI) {
            int nxt = cur + 2; if (nxt >= 3) nxt -= 3;
            STAGE(nxt, (i + 2) * 32);          // overwrites tile i-1's buffer (safe)
        }
        cur = (cur + 1 == 3) ? 0 : cur + 1;
    }
#undef STAGE

    // epilogue: D row = (lane>>4)*4 + j, col = lane&15  (m89-verified layout)
    float bv[4];
#pragma unroll
    for (int n = 0; n < 4; n++) {
        int col = ntile * 128 + wc + n * 16 + fr;
        bv[n] = (col < Nreal) ? bias[col] : 0.0f;
    }
#pragma unroll
    for (int m = 0; m < 4; m++) {
#pragma unroll
        for (int j = 0; j < 4; j++) {
            int r = wr + m * 16 + kc * 4 + j;
#pragma unroll
            for (int n = 0; n < 4; n++) {
                float v = acc[m][n][j] + bv[n];
                if (RELU) v = fmaxf(v, 0.0f);
                int c = wc + n * 16 + fr;
                if (MODE == 2) {
                    if (mtile * 128 + r < cnt) {
                        int col = ntile * 128 + c;
                        if (col < BASE) {
                            int orig = perm[rowbase + r];
                            out32[(size_t)orig * BASE + col] = v;
                        }
                    }
                } else {
                    Obase[(size_t)(rowbase + r) * Npad + ntile * 128 + c] = (half_t)v;
                }
            }
        }
    }
}

// ---------------- launch ----------------
extern "C" void kernel_launch(void* const* d_in, const int* in_sizes, int n_in,
                              void* d_out, int out_size, void* d_ws, size_t ws_size,
                              hipStream_t stream) {
    (void)in_sizes; (void)n_in;
    if (ws_size < WS_NEED) return;

    const float* x    = (const float*)d_in[0];
    const int*   seq  = (const int*)d_in[1];
    const float* Win  = (const float*)d_in[2];
    const float* bin_ = (const float*)d_in[3];
    const float* Wout = (const float*)d_in[4];
    const float* bout = (const float*)d_in[5];
    const float* We1  = (const float*)d_in[6];  const float* be1 = (const float*)d_in[7];
    const float* We2  = (const float*)d_in[8];  const float* be2 = (const float*)d_in[9];
    const float* We3  = (const float*)d_in[10]; const float* be3 = (const float*)d_in[11];
    const float* Wd1  = (const float*)d_in[12]; const float* bd1 = (const float*)d_in[13];
    const float* Wd2  = (const float*)d_in[14]; const float* bd2 = (const float*)d_in[15];
    const float* Wd3  = (const float*)d_in[16]; const float* bd3 = (const float*)d_in[17];

    char* ws = (char*)d_ws;
    int*    meta   = (int*)(ws + OFF_META);
    int*    perm   = (int*)(ws + OFF_PERM);
    int*    rankb  = (int*)(ws + OFF_RANK);
    int*    pos    = (int*)(ws + OFF_POS);
    int*    blkt   = (int*)(ws + OFF_BLKT);
    int*    blkb   = (int*)(ws + OFF_BLKB);
    half_t* xh   = (half_t*)(ws + OFF_XH);
    half_t* E    = (half_t*)(ws + OFF_E);
    half_t* B512 = (half_t*)(ws + OFF_B512);
    half_t* C256 = (half_t*)(ws + OFF_C256);
    half_t* D128 = (half_t*)(ws + OFF_D128);
    half_t* winh = (half_t*)(ws + OFF_WIN);
    half_t* wouth= (half_t*)(ws + OFF_WOUT);
    half_t* we1h = (half_t*)(ws + OFF_WE1);
    half_t* we2h = (half_t*)(ws + OFF_WE2);
    half_t* we3h = (half_t*)(ws + OFF_WE3);
    half_t* wd1h = (half_t*)(ws + OFF_WD1);
    half_t* wd2h = (half_t*)(ws + OFF_WD2);
    half_t* wd3h = (half_t*)(ws + OFF_WD3);
    float*  out  = (float*)d_out;

    hipMemsetAsync(d_out, 0, (size_t)out_size * sizeof(float), stream);

    // deterministic bucket permutation (no atomics)
    rank_kernel<<<NBLK, 256, 0, stream>>>(seq, rankb, blkt);
    base_kernel<<<1, 64, 0, stream>>>(blkt, meta, blkb);
    finalize_kernel<<<NBLK, 256, 0, stream>>>(seq, rankb, blkb, perm, pos);
    zero_xh_pad<<<dim3(128, NB), 256, 0, stream>>>(meta, xh);
    copy_convert_kernel<<<2048, 256, 0, stream>>>(x, pos, xh);

    conv_pad<<<dim3(512, 1, NB), 256, 0, stream>>>(Win,  winh, 1008, 1008, 1024, 10, 1);
    conv_pad<<<dim3(512, 1, NB), 256, 0, stream>>>(Wout, wouth, 1008, 1008, 1024, 10, 2);
    conv_pad<<<dim3(512, 1, 1), 256, 0, stream>>>(We1, we1h,  512, 1008,  512, 10, 0);
    conv_pad<<<dim3(128, 1, 1), 256, 0, stream>>>(We2, we2h,  256,  512,  256,  9, 0);
    conv_pad<<<dim3(64, 1, 1),  256, 0, stream>>>(We3, we3h,  128,  256,  128,  8, 0);
    conv_pad<<<dim3(64, 1, 1),  256, 0, stream>>>(Wd1, wd1h,  256,  128,  256,  7, 0);
    conv_pad<<<dim3(128, 1, 1), 256, 0, stream>>>(Wd2, wd2h,  512,  256,  512,  8, 0);
    conv_pad<<<dim3(512, 1, 1), 256, 0, stream>>>(Wd3, wd3h, 1008,  512, 1024,  9, 0);

    // expand: per-bucket K-trimmed GEMM, xh -> E [.,1024]
    gemm_k<1, false><<<dim3(128, 8, NB), 256, 0, stream>>>(xh, winh, bin_, E, nullptr, meta, perm, 0, 1024, 1008);
    // encoder
    gemm_k<0, true ><<<dim3(MT_DENSE, 4), 256, 0, stream>>>(E,    we1h, be1, B512, nullptr, meta, perm, 1024, 512, 512);
    gemm_k<0, true ><<<dim3(MT_DENSE, 2), 256, 0, stream>>>(B512, we2h, be2, C256, nullptr, meta, perm,  512, 256, 256);
    gemm_k<0, false><<<dim3(MT_DENSE, 1), 256, 0, stream>>>(C256, we3h, be3, D128, nullptr, meta, perm,  256, 128, 128);
    // decoder
    gemm_k<0, true ><<<dim3(MT_DENSE, 2), 256, 0, stream>>>(D128, wd1h, bd1, C256, nullptr, meta, perm,  128, 256, 256);
    gemm_k<0, true ><<<dim3(MT_DENSE, 4), 256, 0, stream>>>(C256, wd2h, bd2, B512, nullptr, meta, perm,  256, 512, 512);
    gemm_k<0, false><<<dim3(MT_DENSE, 8), 256, 0, stream>>>(B512, wd3h, bd3, E,    nullptr, meta, perm,  512, 1024, 1008);
    // contract: per-bucket N-tile-cut GEMM, scatter fp32 rows into pre-zeroed d_out
    gemm_k<2, false><<<dim3(128, 8, NB), 256, 0, stream>>>(E, wouth, bout, nullptr, out, meta, perm, 1024, 1024, 1008);
}